// Round 1
// baseline (94.752 us; speedup 1.0000x reference)
//
#include <hip/hip_runtime.h>

// Problem constants (fixed by the reference).
constexpr int B_ = 128;
constexpr int N_ = 256 * 256;
constexpr int P_ = 1024;
constexpr int T_ = 512;

// One block per (b, d). 512 threads: phase A = gather/compact, phase B = one t per thread.
__global__ __launch_bounds__(512) void apl_kernel(
    const float* __restrict__ dtm,
    const int*  __restrict__ birth_loc,
    const int*  __restrict__ death_loc,
    const int*  __restrict__ ph_dim,
    float*      __restrict__ out)
{
    const int d   = blockIdx.x;   // homology dim 0/1
    const int b   = blockIdx.y;   // sample
    const int tid = threadIdx.x;  // 0..511

    __shared__ float2 cbd[P_];     // compacted (birth, death) values, order-scrambled (ok)
    __shared__ int2   red[512];    // two-smallest-masked-index reduction
    __shared__ int    s_count;
    __shared__ float  s_tmin, s_tmax;

    if (tid == 0) s_count = 0;
    __syncthreads();

    const int*   bl = birth_loc + (size_t)b * P_;
    const int*   dl = death_loc + (size_t)b * P_;
    const int*   pd = ph_dim    + (size_t)b * P_;
    const float* dv = dtm       + (size_t)b * N_;

    const int INF = 0x7fffffff;
    int i1 = INF, i2 = INF;   // thread-local two smallest masked p (sorted: p=tid < p=tid+512)

    #pragma unroll
    for (int r = 0; r < 2; ++r) {
        const int p = tid + r * 512;
        if (pd[p] == d) {
            const float bv = dv[bl[p]];
            const float dvv = dv[dl[p]];
            const int idx = atomicAdd(&s_count, 1);
            cbd[idx] = make_float2(bv, dvv);
            if (i1 == INF) i1 = p; else i2 = p;
        }
    }
    red[tid] = make_int2(i1, i2);
    __syncthreads();

    // Tree-reduce two smallest masked indices. Pairs are sorted (x <= y).
    for (int s = 256; s > 0; s >>= 1) {
        if (tid < s) {
            const int2 a = red[tid];
            const int2 c = red[tid + s];
            const int r1 = min(a.x, c.x);
            const int r2 = min(max(a.x, c.x), min(a.y, c.y));
            red[tid] = make_int2(r1, r2);
        }
        __syncthreads();
    }

    const int cnt = s_count;  // all atomics complete (synced above)

    if (tid == 0) {
        float tmin = 0.0f, tmax = 1.0f;
        if (cnt > 0) {
            const int j1 = red[0].x;
            tmin = dv[bl[j1]];
            tmax = dv[dl[j1]];
            if (cnt > 1) {
                const int j2 = red[0].y;
                tmin = fminf(tmin, dv[bl[j2]]);
                tmax = fmaxf(tmax, dv[dl[j2]]);
            }
        }
        s_tmin = tmin; s_tmax = tmax;
    }
    __syncthreads();

    // ---- Phase B: one t per thread ----
    const float tmin = s_tmin, tmax = s_tmax;
    const float ts = tmin + (tmax - tmin) * ((float)tid * (1.0f / (float)(T_ - 1)));

    // Dual top-2 accumulators (halve the serial max-chain), init 0 == masked-out value.
    float a1 = 0.0f, a2 = 0.0f, c1 = 0.0f, c2 = 0.0f;
    int j = 0;
    for (; j + 2 <= cnt; j += 2) {
        const float2 e0 = cbd[j];
        const float2 e1 = cbd[j + 1];
        const float f0 = fmaxf(fminf(ts - e0.x, e0.y - ts), 0.0f);
        const float f1 = fmaxf(fminf(ts - e1.x, e1.y - ts), 0.0f);
        a2 = fmaxf(a2, fminf(a1, f0)); a1 = fmaxf(a1, f0);
        c2 = fmaxf(c2, fminf(c1, f1)); c1 = fmaxf(c1, f1);
    }
    if (j < cnt) {
        const float2 e0 = cbd[j];
        const float f0 = fmaxf(fminf(ts - e0.x, e0.y - ts), 0.0f);
        a2 = fmaxf(a2, fminf(a1, f0)); a1 = fmaxf(a1, f0);
    }
    const float m1 = fmaxf(a1, c1);
    const float m2 = fmaxf(fminf(a1, c1), fmaxf(a2, c2));

    const size_t o = (((size_t)b * 2 + d) * T_ + tid) * 2;
    if (cnt > 0) {
        out[o]     = m1 + ts;
        out[o + 1] = m2 + ts;
    } else {
        out[o]     = 0.0f;
        out[o + 1] = 0.0f;
    }
}

extern "C" void kernel_launch(void* const* d_in, const int* in_sizes, int n_in,
                              void* d_out, int out_size, void* d_ws, size_t ws_size,
                              hipStream_t stream) {
    const float* dtm = (const float*)d_in[0];
    const int*   bl  = (const int*)d_in[1];
    const int*   dl  = (const int*)d_in[2];
    const int*   pd  = (const int*)d_in[3];
    float*       out = (float*)d_out;

    dim3 grid(2, B_);
    dim3 block(512);
    hipLaunchKernelGGL(apl_kernel, grid, block, 0, stream, dtm, bl, dl, pd, out);
}

// Round 5
// 88.351 us; speedup vs baseline: 1.0724x; 1.0724x over previous
//
#include <hip/hip_runtime.h>

// Problem constants (fixed by the reference).
constexpr int B_ = 128;
constexpr int N_ = 256 * 256;
constexpr int P_ = 1024;
constexpr int T_ = 512;

__device__ __forceinline__ float med3f(float a, float b, float c) {
    return __builtin_amdgcn_fmed3f(a, b, c);
}

// One block per (b, d), 1024 threads (16 waves).
// Phase A: ballot-based ORDERED compaction of masked (birth, death) pairs into LDS (SoA).
// Phase B: 2 threads per t (even/odd lane pair), med3 running top-2, shfl merge.
__global__ __launch_bounds__(1024) void apl_kernel(
    const float* __restrict__ dtm,
    const int*  __restrict__ birth_loc,
    const int*  __restrict__ death_loc,
    const int*  __restrict__ ph_dim,
    float*      __restrict__ out)
{
    const int d    = blockIdx.x;   // homology dim 0/1
    const int b    = blockIdx.y;   // sample
    const int tid  = threadIdx.x;  // 0..1023
    const int lane = tid & 63;
    const int wave = tid >> 6;     // 0..15

    // SoA compacted pairs, float4-aligned, padded to a multiple of 8 with neutral
    // sentinels (birth=+1e30 -> tent very negative -> no effect on running top-2).
    __shared__ float4 sb4[(P_ + 8) / 4];   // 258 float4 = 1032 floats
    __shared__ float4 sd4[(P_ + 8) / 4];
    __shared__ int s_wcnt[16];
    __shared__ int s_wbase[16];
    __shared__ int s_count;
    float* sb = (float*)sb4;
    float* sd = (float*)sd4;

    // Sentinel init (overwritten by compaction on [0, cnt)).
    sb[tid] = 1e30f;
    sd[tid] = -1e30f;
    if (tid < 8) { sb[P_ + tid] = 1e30f; sd[P_ + tid] = -1e30f; }

    const int*   bl = birth_loc + (size_t)b * P_;
    const int*   dl = death_loc + (size_t)b * P_;
    const int*   pd = ph_dim    + (size_t)b * P_;
    const float* dv = dtm       + (size_t)b * N_;

    // ---- Phase A: one pair per thread ----
    // Unconditional coalesced loads: mask + both indices issue together
    // (no serialized mask-load -> index-load dependency).
    const int pdv = pd[tid];
    const int bi  = bl[tid];
    const int di  = dl[tid];
    const bool m  = (pdv == d);
    float bv = 0.0f, dvv = 0.0f;
    if (m) {                       // random gathers only for masked lanes
        bv  = dv[bi];
        dvv = dv[di];
    }
    const unsigned long long mk = __ballot(m);
    const int prefix = __popcll(mk & ((1ull << lane) - 1ull));
    if (lane == 0) s_wcnt[wave] = __popcll(mk);
    __syncthreads();

    if (tid == 0) {                // tiny serial exclusive scan over 16 wave counts
        int run = 0;
        #pragma unroll
        for (int w = 0; w < 16; ++w) { s_wbase[w] = run; run += s_wcnt[w]; }
        s_count = run;
    }
    __syncthreads();

    if (m) {                       // index-ordered compaction (wave order + lane order)
        const int ix = s_wbase[wave] + prefix;
        sb[ix] = bv;
        sd[ix] = dvv;
    }
    __syncthreads();

    // First two masked pairs in index order are simply entries 0 and 1.
    const int cnt = s_count;
    float tmin = 0.0f, tmax = 1.0f;
    if (cnt > 0) {
        tmin = sb[0]; tmax = sd[0];
        if (cnt > 1) { tmin = fminf(tmin, sb[1]); tmax = fmaxf(tmax, sd[1]); }
    }

    // ---- Phase B: lanes 2t / 2t+1 split the pair list, merge via shfl ----
    const int t = tid >> 1;        // 0..511
    const int h = tid & 1;         // which half of the pair list
    const float ts = tmin + (tmax - tmin) * ((float)t * (1.0f / 511.0f));

    // Running top-2 via med3: a2' = med3(a1, a2, f); a1' = max(a1, f).
    // Init (0,0) == the unmasked/clamped zeros of the reference; negative f is a no-op.
    float a1 = 0.0f, a2 = 0.0f, c1 = 0.0f, c2 = 0.0f;
    const int kmax = (cnt + 7) >> 3;   // each iter: 4 elements per thread, 8 per pair
    int idx = h;                       // float4 block 2k + h
    for (int k = 0; k < kmax; ++k, idx += 2) {
        const float4 bb = sb4[idx];
        const float4 dd = sd4[idx];
        float f;
        f = fminf(ts - bb.x, dd.x - ts); a2 = med3f(a1, a2, f); a1 = fmaxf(a1, f);
        f = fminf(ts - bb.y, dd.y - ts); c2 = med3f(c1, c2, f); c1 = fmaxf(c1, f);
        f = fminf(ts - bb.z, dd.z - ts); a2 = med3f(a1, a2, f); a1 = fmaxf(a1, f);
        f = fminf(ts - bb.w, dd.w - ts); c2 = med3f(c1, c2, f); c1 = fmaxf(c1, f);
    }
    // merge the two in-thread chains
    const float m1 = fmaxf(a1, c1);
    const float m2 = fmaxf(fminf(a1, c1), fmaxf(a2, c2));
    // merge across the lane pair (same wave: lanes 2t, 2t+1)
    const float p1 = __shfl_xor(m1, 1);
    const float p2 = __shfl_xor(m2, 1);
    const float M1 = fmaxf(m1, p1);
    const float M2 = fmaxf(fminf(m1, p1), fmaxf(m2, p2));

    float val = (h == 0) ? M1 : M2;
    val = (cnt > 0) ? (val + ts) : 0.0f;
    out[(((size_t)b * 2 + d) * T_ + t) * 2 + h] = val;   // fully coalesced
}

extern "C" void kernel_launch(void* const* d_in, const int* in_sizes, int n_in,
                              void* d_out, int out_size, void* d_ws, size_t ws_size,
                              hipStream_t stream) {
    const float* dtm = (const float*)d_in[0];
    const int*   bl  = (const int*)d_in[1];
    const int*   dl  = (const int*)d_in[2];
    const int*   pd  = (const int*)d_in[3];
    float*       out = (float*)d_out;

    dim3 grid(2, B_);
    dim3 block(1024);
    hipLaunchKernelGGL(apl_kernel, grid, block, 0, stream, dtm, bl, dl, pd, out);
}

// Round 6
// 86.042 us; speedup vs baseline: 1.1012x; 1.0268x over previous
//
#include <hip/hip_runtime.h>

// Problem constants (fixed by the reference).
constexpr int B_ = 128;
constexpr int N_ = 256 * 256;
constexpr int P_ = 1024;
constexpr int T_ = 512;

__device__ __forceinline__ float med3f(float a, float b, float c) {
    return __builtin_amdgcn_fmed3f(a, b, c);
}

// One block per (b, d), 1024 threads (16 waves).
// Phase A: ballot-based ORDERED compaction of masked pairs into LDS as
//          (midpoint, halfwidth) SoA: tent f = w - |ts - m|  (2 VALU ops).
// Phase B: 2 threads per t (even/odd lane pair); 4 independent med3 top-2
//          chains; 2x-unrolled float4 reads; shfl merge.
__global__ __launch_bounds__(1024) void apl_kernel(
    const float* __restrict__ dtm,
    const int*  __restrict__ birth_loc,
    const int*  __restrict__ death_loc,
    const int*  __restrict__ ph_dim,
    float*      __restrict__ out)
{
    const int d    = blockIdx.x;   // homology dim 0/1
    const int b    = blockIdx.y;   // sample
    const int tid  = threadIdx.x;  // 0..1023
    const int lane = tid & 63;
    const int wave = tid >> 6;     // 0..15

    // SoA (m, w), padded to a multiple of 16 elems with neutral sentinels
    // (w = -1e30 -> f = -1e30 - |ts - 0| : strongly negative, no effect).
    __shared__ float4 sm4[(P_ + 16) / 4];   // 260 float4 = 1040 floats
    __shared__ float4 sw4[(P_ + 16) / 4];
    __shared__ float2 s_bd01[2];            // raw (birth, death) of entries 0,1 (exact tmin/tmax)
    __shared__ int s_wcnt[16];
    __shared__ int s_wbase[16];
    __shared__ int s_count;
    float* sm = (float*)sm4;
    float* sw = (float*)sw4;

    // Sentinel init (overwritten by compaction on [0, cnt)).
    sm[tid] = 0.0f;
    sw[tid] = -1e30f;
    if (tid < 16) { sm[P_ + tid] = 0.0f; sw[P_ + tid] = -1e30f; }

    const int*   bl = birth_loc + (size_t)b * P_;
    const int*   dl = death_loc + (size_t)b * P_;
    const int*   pd = ph_dim    + (size_t)b * P_;
    const float* dv = dtm       + (size_t)b * N_;

    // ---- Phase A ----
    // Unconditional coalesced loads: mask + both indices issue together.
    const int pdv = pd[tid];
    const int bi  = bl[tid];
    const int di  = dl[tid];
    const bool msk = (pdv == d);
    float bv = 0.0f, dvv = 0.0f;
    if (msk) {                     // random gathers only for masked lanes
        bv  = dv[bi];
        dvv = dv[di];
    }
    const unsigned long long mk = __ballot(msk);
    const int prefix = __popcll(mk & ((1ull << lane) - 1ull));
    if (lane == 0) s_wcnt[wave] = __popcll(mk);
    __syncthreads();

    if (tid == 0) {                // tiny serial exclusive scan over 16 wave counts
        int run = 0;
        #pragma unroll
        for (int w = 0; w < 16; ++w) { s_wbase[w] = run; run += s_wcnt[w]; }
        s_count = run;
    }
    __syncthreads();

    if (msk) {                     // index-ordered compaction (wave order + lane order)
        const int ix = s_wbase[wave] + prefix;
        sm[ix] = (bv + dvv) * 0.5f;
        sw[ix] = (dvv - bv) * 0.5f;
        if (ix < 2) s_bd01[ix] = make_float2(bv, dvv);  // exact values for tmin/tmax
    }
    __syncthreads();

    const int cnt = s_count;
    float tmin = 0.0f, tmax = 1.0f;
    if (cnt > 0) {
        tmin = s_bd01[0].x; tmax = s_bd01[0].y;
        if (cnt > 1) { tmin = fminf(tmin, s_bd01[1].x); tmax = fmaxf(tmax, s_bd01[1].y); }
    }

    // ---- Phase B: lanes 2t / 2t+1 split the pair list ----
    const int t = tid >> 1;        // 0..511
    const int h = tid & 1;         // which half of the float4-block stream
    const float ts = tmin + (tmax - tmin) * ((float)t * (1.0f / 511.0f));

    // Four independent running top-2 chains (one per float4 slot).
    // Update: a2' = med3(a1, a2, f); a1' = max(a1, f). Init (0,0) == reference zeros.
    float a1 = 0.0f, a2 = 0.0f, c1 = 0.0f, c2 = 0.0f;
    float e1 = 0.0f, e2 = 0.0f, g1 = 0.0f, g2 = 0.0f;
    const int kmax = (cnt + 15) >> 4;  // 8 elems per thread per iter (16 per pair)
    int idx = 2 * h;                   // float4 blocks 4k+2h, 4k+2h+1
    for (int k = 0; k < kmax; ++k, idx += 4) {
        const float4 ma = sm4[idx];
        const float4 wa = sw4[idx];
        const float4 mb = sm4[idx + 1];
        const float4 wb = sw4[idx + 1];
        float f;
        f = wa.x - fabsf(ts - ma.x); a2 = med3f(a1, a2, f); a1 = fmaxf(a1, f);
        f = wa.y - fabsf(ts - ma.y); c2 = med3f(c1, c2, f); c1 = fmaxf(c1, f);
        f = wa.z - fabsf(ts - ma.z); e2 = med3f(e1, e2, f); e1 = fmaxf(e1, f);
        f = wa.w - fabsf(ts - ma.w); g2 = med3f(g1, g2, f); g1 = fmaxf(g1, f);
        f = wb.x - fabsf(ts - mb.x); a2 = med3f(a1, a2, f); a1 = fmaxf(a1, f);
        f = wb.y - fabsf(ts - mb.y); c2 = med3f(c1, c2, f); c1 = fmaxf(c1, f);
        f = wb.z - fabsf(ts - mb.z); e2 = med3f(e1, e2, f); e1 = fmaxf(e1, f);
        f = wb.w - fabsf(ts - mb.w); g2 = med3f(g1, g2, f); g1 = fmaxf(g1, f);
    }
    // merge 4 chains -> 2 -> 1
    const float x1 = fmaxf(a1, c1);
    const float x2 = fmaxf(fminf(a1, c1), fmaxf(a2, c2));
    const float y1 = fmaxf(e1, g1);
    const float y2 = fmaxf(fminf(e1, g1), fmaxf(e2, g2));
    const float m1 = fmaxf(x1, y1);
    const float m2 = fmaxf(fminf(x1, y1), fmaxf(x2, y2));
    // merge across the lane pair (same wave: lanes 2t, 2t+1)
    const float p1 = __shfl_xor(m1, 1);
    const float p2 = __shfl_xor(m2, 1);
    const float M1 = fmaxf(m1, p1);
    const float M2 = fmaxf(fminf(m1, p1), fmaxf(m2, p2));

    float val = (h == 0) ? M1 : M2;
    val = (cnt > 0) ? (val + ts) : 0.0f;
    out[(((size_t)b * 2 + d) * T_ + t) * 2 + h] = val;   // fully coalesced
}

extern "C" void kernel_launch(void* const* d_in, const int* in_sizes, int n_in,
                              void* d_out, int out_size, void* d_ws, size_t ws_size,
                              hipStream_t stream) {
    const float* dtm = (const float*)d_in[0];
    const int*   bl  = (const int*)d_in[1];
    const int*   dl  = (const int*)d_in[2];
    const int*   pd  = (const int*)d_in[3];
    float*       out = (float*)d_out;

    dim3 grid(2, B_);
    dim3 block(1024);
    hipLaunchKernelGGL(apl_kernel, grid, block, 0, stream, dtm, bl, dl, pd, out);
}

// Round 7
// 82.968 us; speedup vs baseline: 1.1420x; 1.0370x over previous
//
#include <hip/hip_runtime.h>

// Problem constants (fixed by the reference).
constexpr int B_ = 128;
constexpr int N_ = 256 * 256;
constexpr int P_ = 1024;
constexpr int T_ = 512;

__device__ __forceinline__ float med3f(float a, float b, float c) {
    return __builtin_amdgcn_fmed3f(a, b, c);
}

// One block per (b, d), 1024 threads (16 waves).
// Phase A: ballot-based ORDERED compaction of masked pairs. Two orderings:
//   - all-masked (for exact first-2 pairs -> tmin/tmax, and count>0 gate)
//   - filtered (death > birth only) -> scan list as (midpoint, halfwidth) SoA.
//     Pairs with w<=0 have tent <= 0 everywhere; accumulators start at 0, so
//     dropping them is exact. Halves the scan list for uniform random data.
// Phase B: 2 threads per t; 4 independent med3 top-2 chains; 2x float4 unroll.
__global__ __launch_bounds__(1024) void apl_kernel(
    const float* __restrict__ dtm,
    const int*  __restrict__ birth_loc,
    const int*  __restrict__ death_loc,
    const int*  __restrict__ ph_dim,
    float*      __restrict__ out)
{
    const int d    = blockIdx.x;   // homology dim 0/1
    const int b    = blockIdx.y;   // sample
    const int tid  = threadIdx.x;  // 0..1023
    const int lane = tid & 63;
    const int wave = tid >> 6;     // 0..15

    // SoA (m, w) scan list, padded to a multiple of 16 elems with neutral
    // sentinels (w = -1e30 -> f strongly negative, no effect).
    __shared__ float4 sm4[(P_ + 16) / 4];   // 260 float4 = 1040 floats
    __shared__ float4 sw4[(P_ + 16) / 4];
    __shared__ float2 s_bd01[2];            // raw (birth, death) of all-masked entries 0,1
    __shared__ int s_wcntA[16];             // all-masked per-wave counts
    __shared__ int s_wcntS[16];             // filtered per-wave counts
    __shared__ int s_wbaseA[16];
    __shared__ int s_wbaseS[16];
    __shared__ int s_cntA;                  // all-masked count (count>0 gate)
    __shared__ int s_cntS;                  // filtered count (scan length)
    float* sm = (float*)sm4;
    float* sw = (float*)sw4;

    // Sentinel init (overwritten by compaction on [0, cntS)).
    sm[tid] = 0.0f;
    sw[tid] = -1e30f;
    if (tid < 16) { sm[P_ + tid] = 0.0f; sw[P_ + tid] = -1e30f; }

    const int*   bl = birth_loc + (size_t)b * P_;
    const int*   dl = death_loc + (size_t)b * P_;
    const int*   pd = ph_dim    + (size_t)b * P_;
    const float* dv = dtm       + (size_t)b * N_;

    // ---- Phase A ----
    const int pdv = pd[tid];
    const int bi  = bl[tid];
    const int di  = dl[tid];
    const bool msk = (pdv == d);
    float bv = 0.0f, dvv = 0.0f;
    if (msk) {                     // random gathers only for masked lanes
        bv  = dv[bi];
        dvv = dv[di];
    }
    const bool live = msk && (dvv > bv);   // pairs that can ever have tent > 0

    const unsigned long long mkA = __ballot(msk);
    const unsigned long long mkS = __ballot(live);
    const unsigned long long below = (1ull << lane) - 1ull;
    const int prefA = __popcll(mkA & below);
    const int prefS = __popcll(mkS & below);
    if (lane == 0) { s_wcntA[wave] = __popcll(mkA); s_wcntS[wave] = __popcll(mkS); }
    __syncthreads();

    if (tid == 0) {                // serial exclusive scans over 16 wave counts
        int ra = 0, rs = 0;
        #pragma unroll
        for (int w = 0; w < 16; ++w) {
            s_wbaseA[w] = ra; ra += s_wcntA[w];
            s_wbaseS[w] = rs; rs += s_wcntS[w];
        }
        s_cntA = ra; s_cntS = rs;
    }
    __syncthreads();

    if (msk) {
        const int ixA = s_wbaseA[wave] + prefA;
        if (ixA < 2) s_bd01[ixA] = make_float2(bv, dvv);  // exact tmin/tmax source
    }
    if (live) {                    // filtered, index-ordered compaction
        const int ix = s_wbaseS[wave] + prefS;
        sm[ix] = (bv + dvv) * 0.5f;
        sw[ix] = (dvv - bv) * 0.5f;
    }
    __syncthreads();

    const int cntA = s_cntA;       // gate + tmin/tmax semantics use ALL masked pairs
    const int cntS = s_cntS;       // scan list length
    float tmin = 0.0f, tmax = 1.0f;
    if (cntA > 0) {
        tmin = s_bd01[0].x; tmax = s_bd01[0].y;
        if (cntA > 1) { tmin = fminf(tmin, s_bd01[1].x); tmax = fmaxf(tmax, s_bd01[1].y); }
    }

    // ---- Phase B: lanes 2t / 2t+1 split the scan list ----
    const int t = tid >> 1;        // 0..511
    const int h = tid & 1;
    const float ts = tmin + (tmax - tmin) * ((float)t * (1.0f / 511.0f));

    // Four independent running top-2 chains (one per float4 slot).
    // Update: a2' = med3(a1, a2, f); a1' = max(a1, f). Init (0,0) == reference zeros.
    float a1 = 0.0f, a2 = 0.0f, c1 = 0.0f, c2 = 0.0f;
    float e1 = 0.0f, e2 = 0.0f, g1 = 0.0f, g2 = 0.0f;
    const int kmax = (cntS + 15) >> 4;  // 8 elems per thread per iter (16 per pair)
    int idx = 2 * h;                    // float4 blocks 4k+2h, 4k+2h+1
    for (int k = 0; k < kmax; ++k, idx += 4) {
        const float4 ma = sm4[idx];
        const float4 wa = sw4[idx];
        const float4 mb = sm4[idx + 1];
        const float4 wb = sw4[idx + 1];
        float f;
        f = wa.x - fabsf(ts - ma.x); a2 = med3f(a1, a2, f); a1 = fmaxf(a1, f);
        f = wa.y - fabsf(ts - ma.y); c2 = med3f(c1, c2, f); c1 = fmaxf(c1, f);
        f = wa.z - fabsf(ts - ma.z); e2 = med3f(e1, e2, f); e1 = fmaxf(e1, f);
        f = wa.w - fabsf(ts - ma.w); g2 = med3f(g1, g2, f); g1 = fmaxf(g1, f);
        f = wb.x - fabsf(ts - mb.x); a2 = med3f(a1, a2, f); a1 = fmaxf(a1, f);
        f = wb.y - fabsf(ts - mb.y); c2 = med3f(c1, c2, f); c1 = fmaxf(c1, f);
        f = wb.z - fabsf(ts - mb.z); e2 = med3f(e1, e2, f); e1 = fmaxf(e1, f);
        f = wb.w - fabsf(ts - mb.w); g2 = med3f(g1, g2, f); g1 = fmaxf(g1, f);
    }
    // merge 4 chains -> 2 -> 1
    const float x1 = fmaxf(a1, c1);
    const float x2 = fmaxf(fminf(a1, c1), fmaxf(a2, c2));
    const float y1 = fmaxf(e1, g1);
    const float y2 = fmaxf(fminf(e1, g1), fmaxf(e2, g2));
    const float m1 = fmaxf(x1, y1);
    const float m2 = fmaxf(fminf(x1, y1), fmaxf(x2, y2));
    // merge across the lane pair (same wave: lanes 2t, 2t+1)
    const float p1 = __shfl_xor(m1, 1);
    const float p2 = __shfl_xor(m2, 1);
    const float M1 = fmaxf(m1, p1);
    const float M2 = fmaxf(fminf(m1, p1), fmaxf(m2, p2));

    float val = (h == 0) ? M1 : M2;
    val = (cntA > 0) ? (val + ts) : 0.0f;
    out[(((size_t)b * 2 + d) * T_ + t) * 2 + h] = val;   // fully coalesced
}

extern "C" void kernel_launch(void* const* d_in, const int* in_sizes, int n_in,
                              void* d_out, int out_size, void* d_ws, size_t ws_size,
                              hipStream_t stream) {
    const float* dtm = (const float*)d_in[0];
    const int*   bl  = (const int*)d_in[1];
    const int*   dl  = (const int*)d_in[2];
    const int*   pd  = (const int*)d_in[3];
    float*       out = (float*)d_out;

    dim3 grid(2, B_);
    dim3 block(1024);
    hipLaunchKernelGGL(apl_kernel, grid, block, 0, stream, dtm, bl, dl, pd, out);
}